// Round 1
// baseline (1117.848 us; speedup 1.0000x reference)
//
#include <hip/hip_runtime.h>
#include <stdint.h>

// WindowAttention (focal) on gfx950.
// Pipeline: k_setup -> k_qkv_main -> k_qkv_pool -> k_attn -> k_proj
// Internal compute bf16 MFMA (16x16x32), fp32 accumulate. ws usage ~157 MB.

#define DIM 192
#define HEADS 6
#define HD 32
#define WA 49
#define NKEY 230
#define SSTR 272                 // S row stride in shorts (bank-staggered, 16B-aligned)
#define SCALE_F 0.17677669529663687f

typedef __attribute__((ext_vector_type(8))) short bf16x8;  // 8 bf16 in 4 VGPRs
typedef __attribute__((ext_vector_type(4))) float f32x4;

__device__ __forceinline__ short f2bf(float f) {
  union { float f; uint32_t u; } v; v.f = f;
  uint32_t u = v.u;
  return (short)((u + 0x7FFFu + ((u >> 16) & 1u)) >> 16);  // RNE
}
__device__ __forceinline__ float bf2f(short h) {
  union { uint32_t u; float f; } v; v.u = ((uint32_t)(uint16_t)h) << 16;
  return v.f;
}

// ---------------- setup: bf16 weights, ring table, bias table ----------------
__global__ __launch_bounds__(256) void k_setup(
    const float* __restrict__ qkv_w, const float* __restrict__ proj_w,
    const float* __restrict__ rpb_table, const float* __restrict__ rpb_nb,
    const float* __restrict__ rpb_win,
    short* __restrict__ w1, short* __restrict__ w2,
    int2* __restrict__ ring, float* __restrict__ bias_tbl) {
  const int tid = blockIdx.x * blockDim.x + threadIdx.x;
  const int nth = gridDim.x * blockDim.x;
  for (int i = tid; i < 576 * DIM; i += nth) w1[i] = f2bf(qkv_w[i]);
  for (int i = tid; i < DIM * DIM; i += nth) w2[i] = f2bf(proj_w[i]);
  // rolled-ring gather table: 132 valid (shift,r,c) -> (dr,dc) rel. window origin
  for (int e = tid; e < 132; e += nth) {
    int cnt = 0, fdr = 0, fdc = 0;
    for (int idx = 0; idx < 196; ++idx) {
      int s = idx / 49, rc = idx % 49, r = rc / 7, c = rc % 7;
      bool valid;
      if (s == 0)      valid = (r >= 4) || (c >= 4);   // roll(-3,-3): src +3,+3
      else if (s == 1) valid = (r >= 4) || (c < 3);    // roll(-3,+3): src +3,-3
      else if (s == 2) valid = (r < 3)  || (c >= 4);   // roll(+3,-3): src -3,+3
      else             valid = (r < 3)  || (c < 3);    // roll(+3,+3): src -3,-3
      if (valid) {
        if (cnt == e) { fdr = r + ((s < 2) ? 3 : -3); fdc = c + (((s & 1) == 0) ? 3 : -3); }
        ++cnt;
      }
    }
    ring[e] = make_int2(fdr, fdc);
  }
  // bias_tbl[h][r][kk], kk in [0,230)
  for (int i = tid; i < HEADS * WA * NKEY; i += nth) {
    int kk = i % NKEY, rem = i / NKEY, r = rem % WA, h = rem / WA;
    float bv;
    if (kk < 49) {
      int ar = r / 7, ac = r % 7, br = kk / 7, bc = kk % 7;
      bv = rpb_table[((ar - br + 6) * 13 + (ac - bc + 6)) * HEADS + h];
    } else if (kk < 181) {
      bv = rpb_nb[((size_t)h * WA + r) * 132 + (kk - 49)];
    } else {
      int p = kk - 181;
      int ar = r / 7, ac = r % 7, br = p / 7, bc = p % 7;
      bv = rpb_win[h * 169 + (ar - br + 6) * 13 + (ac - bc + 6)];
    }
    bias_tbl[i] = bv;
  }
}

// ---------------- QKV on fine map: M=100352, N=576, K=192 ----------------
__global__ __launch_bounds__(256) void k_qkv_main(
    const float* __restrict__ x, const short* __restrict__ w1, const float* __restrict__ qkv_b,
    short* __restrict__ qw, short* __restrict__ kn, short* __restrict__ vn) {
  const int tid = threadIdx.x;
  const int wave = tid >> 6, lane = tid & 63, quad = lane >> 4, l16 = lane & 15;
  const int mbase = (blockIdx.x * 4 + wave) * 16;

  bf16x8 afr[6];
  {
    const float* xrow = x + (size_t)(mbase + l16) * DIM + quad * 8;
#pragma unroll
    for (int ks = 0; ks < 6; ++ks) {
      float4 f0 = *(const float4*)(xrow + ks * 32);
      float4 f1 = *(const float4*)(xrow + ks * 32 + 4);
      bf16x8 a;
      a[0] = f2bf(f0.x); a[1] = f2bf(f0.y); a[2] = f2bf(f0.z); a[3] = f2bf(f0.w);
      a[4] = f2bf(f1.x); a[5] = f2bf(f1.y); a[6] = f2bf(f1.z); a[7] = f2bf(f1.w);
      afr[ks] = a;
    }
  }
  size_t q_base[4], kv_base[4];
#pragma unroll
  for (int rg = 0; rg < 4; ++rg) {
    int m = mbase + quad * 4 + rg;
    int bb = m / 12544, rem = m % 12544;
    int i = rem / 112, j = rem % 112;
    int wr = i / 7, rr = i % 7, wc = j / 7, cc = j % 7;
    int winid = (bb * 16 + wr) * 16 + wc;
    q_base[rg]  = ((size_t)winid * WA + (rr * 7 + cc)) * DIM;
    kv_base[rg] = (size_t)m * DIM;
  }
  for (int nt = 0; nt < 36; ++nt) {
    const int n = nt * 16 + l16;
    const short* wrow = w1 + (size_t)n * DIM + quad * 8;
    f32x4 acc = {0.f, 0.f, 0.f, 0.f};
#pragma unroll
    for (int ks = 0; ks < 6; ++ks)
      acc = __builtin_amdgcn_mfma_f32_16x16x32_bf16(afr[ks], *(const bf16x8*)(wrow + ks * 32), acc, 0, 0, 0);
    const float bias = qkv_b[n];
#pragma unroll
    for (int rg = 0; rg < 4; ++rg) {
      float vo = acc[rg] + bias;
      if (nt < 12)      qw[q_base[rg] + n]            = f2bf(vo * SCALE_F);  // fold q scale
      else if (nt < 24) kn[kv_base[rg] + (n - 192)]   = f2bf(vo);
      else              vn[kv_base[rg] + (n - 384)]   = f2bf(vo);
    }
  }
}

// ---------------- QKV on pooled map: M=2048, only k,v ----------------
__global__ __launch_bounds__(256) void k_qkv_pool(
    const float* __restrict__ xp, const short* __restrict__ w1, const float* __restrict__ qkv_b,
    short* __restrict__ kp, short* __restrict__ vp) {
  const int tid = threadIdx.x;
  const int wave = tid >> 6, lane = tid & 63, quad = lane >> 4, l16 = lane & 15;
  const int mbase = (blockIdx.x * 4 + wave) * 16;

  bf16x8 afr[6];
  {
    const float* xrow = xp + (size_t)(mbase + l16) * DIM + quad * 8;
#pragma unroll
    for (int ks = 0; ks < 6; ++ks) {
      float4 f0 = *(const float4*)(xrow + ks * 32);
      float4 f1 = *(const float4*)(xrow + ks * 32 + 4);
      bf16x8 a;
      a[0] = f2bf(f0.x); a[1] = f2bf(f0.y); a[2] = f2bf(f0.z); a[3] = f2bf(f0.w);
      a[4] = f2bf(f1.x); a[5] = f2bf(f1.y); a[6] = f2bf(f1.z); a[7] = f2bf(f1.w);
      afr[ks] = a;
    }
  }
  for (int nt = 12; nt < 36; ++nt) {
    const int n = nt * 16 + l16;
    const short* wrow = w1 + (size_t)n * DIM + quad * 8;
    f32x4 acc = {0.f, 0.f, 0.f, 0.f};
#pragma unroll
    for (int ks = 0; ks < 6; ++ks)
      acc = __builtin_amdgcn_mfma_f32_16x16x32_bf16(afr[ks], *(const bf16x8*)(wrow + ks * 32), acc, 0, 0, 0);
    const float bias = qkv_b[n];
#pragma unroll
    for (int rg = 0; rg < 4; ++rg) {
      int m = mbase + quad * 4 + rg;
      float vo = acc[rg] + bias;
      if (nt < 24) kp[(size_t)m * DIM + (n - 192)] = f2bf(vo);
      else         vp[(size_t)m * DIM + (n - 384)] = f2bf(vo);
    }
  }
}

// ---------------- attention: one block per (window, head) ----------------
__global__ __launch_bounds__(256) void k_attn(
    const short* __restrict__ qw, const short* __restrict__ kn, const short* __restrict__ vn,
    const short* __restrict__ kp, const short* __restrict__ vp,
    const float* __restrict__ bias_tbl, const int2* __restrict__ ring,
    short* __restrict__ ao) {
  __shared__ short k_l[240 * 32];    // [key][ch]  (pad keys 230..239 = 0)
  __shared__ short vT_l[32 * 256];   // [ch][key]  (pad keys 230..255 = 0)
  __shared__ short q_l[64 * 32];     // [row][ch]  (pad rows 49..63 = 0)
  __shared__ short S_l[64 * SSTR];   // bf16 logits, then P in-place
  __shared__ float pmask[64];
  __shared__ float red_m[256];
  __shared__ float red_s[256];

  const int tid = threadIdx.x;
  const int bid = blockIdx.x;
  const int win = bid / HEADS;
  const int h   = bid - win * HEADS;
  const int b   = win >> 8;
  const int wr  = (win >> 4) & 15;
  const int wc  = win & 15;

  // phase 0: zero staging buffers (pad regions must be exactly 0)
  {
    const int4 z = {0, 0, 0, 0};
    for (int i = tid * 8; i < 240 * 32; i += 256 * 8) *(int4*)&k_l[i] = z;
    for (int i = tid * 8; i < 32 * 256; i += 256 * 8) *(int4*)&vT_l[i] = z;
    for (int i = tid * 8; i < 64 * 32;  i += 256 * 8) *(int4*)&q_l[i]  = z;
  }
  __syncthreads();

  // phase 1: gather q, K, V^T, pool mask
  if (tid < 64) {
    float pm = 0.f;
    if (tid < WA) {
      int pi = wr - 3 + tid / 7, pj = wc - 3 + tid % 7;
      if (pi < 0 || pi >= 16 || pj < 0 || pj >= 16) pm = -100.f;
    }
    pmask[tid] = pm;
  }
  if (tid < 196) {
    int r = tid >> 2, part = tid & 3;
    *(int4*)&q_l[r * 32 + part * 8] =
        *(const int4*)(qw + ((size_t)win * WA + r) * DIM + h * HD + part * 8);
  }
  {
    const int part = tid & 3;
    const int choff = h * HD + part * 8;
    for (int it = 0; it < 4; ++it) {
      int kk = it * 64 + (tid >> 2);
      if (kk < NKEY) {
        const short* ksrc = nullptr; const short* vsrc = nullptr;
        if (kk < WA) {                      // in-window
          int i = wr * 7 + kk / 7, j = wc * 7 + kk % 7;
          size_t t = ((size_t)(b * 112 + i)) * 112 + j;
          ksrc = kn + t * DIM + choff; vsrc = vn + t * DIM + choff;
        } else if (kk < 181) {              // rolled ring (circular wrap, matches jnp.roll)
          int2 rr = ring[kk - 49];
          int i = wr * 7 + rr.x; if (i < 0) i += 112; if (i >= 112) i -= 112;
          int j = wc * 7 + rr.y; if (j < 0) j += 112; if (j >= 112) j -= 112;
          size_t t = ((size_t)(b * 112 + i)) * 112 + j;
          ksrc = kn + t * DIM + choff; vsrc = vn + t * DIM + choff;
        } else {                            // pooled 7x7 neighborhood (zero if OOB)
          int p = kk - 181;
          int i = wr - 3 + p / 7, j = wc - 3 + p % 7;
          if (i >= 0 && i < 16 && j >= 0 && j < 16) {
            size_t t = ((size_t)(b * 16 + i)) * 16 + j;
            ksrc = kp + t * DIM + choff; vsrc = vp + t * DIM + choff;
          }
        }
        if (ksrc) {
          int4 kvv = *(const int4*)ksrc;
          *(int4*)&k_l[kk * 32 + part * 8] = kvv;
          int4 vvv = *(const int4*)vsrc;
          const short* vs = (const short*)&vvv;
#pragma unroll
          for (int e = 0; e < 8; ++e) vT_l[(part * 8 + e) * 256 + kk] = vs[e];
        }
      }
    }
  }
  __syncthreads();

  const int wave = tid >> 6, lane = tid & 63, quad = lane >> 4, l16 = lane & 15;

  // phase 2: S = q K^T  (wave = m-tile; K-dim = hd = 32 = one MFMA)
  {
    bf16x8 qfr = *(const bf16x8*)&q_l[(wave * 16 + l16) * 32 + quad * 8];
#pragma unroll
    for (int nt = 0; nt < 15; ++nt) {
      bf16x8 kfr = *(const bf16x8*)&k_l[(nt * 16 + l16) * 32 + quad * 8];
      f32x4 acc = {0.f, 0.f, 0.f, 0.f};
      acc = __builtin_amdgcn_mfma_f32_16x16x32_bf16(qfr, kfr, acc, 0, 0, 0);
#pragma unroll
      for (int rg = 0; rg < 4; ++rg)
        S_l[(wave * 16 + quad * 4 + rg) * SSTR + nt * 16 + l16] = f2bf(acc[rg]);
    }
    // zero pad cols 240..255 (PV reads K=256; MFMA only wrote 0..239)
    int rr = tid >> 2, c0 = 240 + (tid & 3) * 4;
    *(int2*)&S_l[rr * SSTR + c0] = make_int2(0, 0);
  }
  __syncthreads();

  // phase 3: bias + pool mask + softmax, rows x 4 key-segments (one per wave)
  {
    const int r = lane, seg = wave;
    const int kbeg = seg * 58;
    int kend = kbeg + 58; if (kend > NKEY) kend = NKEY;
    float mloc = -1e30f;
    if (r < WA) {
      const float* brow = bias_tbl + (size_t)(h * WA + r) * NKEY;
      for (int kk = kbeg; kk < kend; ++kk) {
        float sv = bf2f(S_l[r * SSTR + kk]) + brow[kk];
        if (kk >= 181) sv += pmask[kk - 181];
        S_l[r * SSTR + kk] = f2bf(sv);
        mloc = fmaxf(mloc, sv);
      }
    }
    red_m[tid] = mloc;
    __syncthreads();
    const float mrow = fmaxf(fmaxf(red_m[r], red_m[64 + r]),
                             fmaxf(red_m[128 + r], red_m[192 + r]));
    float sloc = 0.f;
    if (r < WA)
      for (int kk = kbeg; kk < kend; ++kk)
        sloc += __expf(bf2f(S_l[r * SSTR + kk]) - mrow);
    red_s[tid] = sloc;
    __syncthreads();
    if (r < WA) {
      const float inv = 1.f / (red_s[r] + red_s[64 + r] + red_s[128 + r] + red_s[192 + r]);
      for (int kk = kbeg; kk < kend; ++kk)
        S_l[r * SSTR + kk] = f2bf(__expf(bf2f(S_l[r * SSTR + kk]) - mrow) * inv);
    }
  }
  __syncthreads();

  // phase 4: O = P V  (K padded to 256, pad P == 0)
#pragma unroll
  for (int nt2 = 0; nt2 < 2; ++nt2) {
    f32x4 acc = {0.f, 0.f, 0.f, 0.f};
#pragma unroll
    for (int k0 = 0; k0 < 8; ++k0) {
      bf16x8 pfr = *(const bf16x8*)&S_l[(wave * 16 + l16) * SSTR + k0 * 32 + quad * 8];
      bf16x8 vfr = *(const bf16x8*)&vT_l[(nt2 * 16 + l16) * 256 + k0 * 32 + quad * 8];
      acc = __builtin_amdgcn_mfma_f32_16x16x32_bf16(pfr, vfr, acc, 0, 0, 0);
    }
#pragma unroll
    for (int rg = 0; rg < 4; ++rg) {
      int row = wave * 16 + quad * 4 + rg;
      if (row < WA)
        ao[((size_t)win * WA + row) * DIM + h * HD + nt2 * 16 + l16] = f2bf(acc[rg]);
    }
  }
}

// ---------------- proj: M=100352, N=192, K=192, fp32 out ----------------
__global__ __launch_bounds__(256) void k_proj(
    const short* __restrict__ ao, const short* __restrict__ w2, const float* __restrict__ pb,
    float* __restrict__ out) {
  const int tid = threadIdx.x;
  const int wave = tid >> 6, lane = tid & 63, quad = lane >> 4, l16 = lane & 15;
  const int mbase = (blockIdx.x * 4 + wave) * 16;
  bf16x8 afr[6];
  const short* arow = ao + (size_t)(mbase + l16) * DIM + quad * 8;
#pragma unroll
  for (int ks = 0; ks < 6; ++ks) afr[ks] = *(const bf16x8*)(arow + ks * 32);
  for (int nt = 0; nt < 12; ++nt) {
    const int n = nt * 16 + l16;
    const short* wrow = w2 + (size_t)n * DIM + quad * 8;
    f32x4 acc = {0.f, 0.f, 0.f, 0.f};
#pragma unroll
    for (int ks = 0; ks < 6; ++ks)
      acc = __builtin_amdgcn_mfma_f32_16x16x32_bf16(afr[ks], *(const bf16x8*)(wrow + ks * 32), acc, 0, 0, 0);
    const float bias = pb[n];
#pragma unroll
    for (int rg = 0; rg < 4; ++rg)
      out[(size_t)(mbase + quad * 4 + rg) * DIM + n] = acc[rg] + bias;
  }
}

extern "C" void kernel_launch(void* const* d_in, const int* in_sizes, int n_in,
                              void* d_out, int out_size, void* d_ws, size_t ws_size,
                              hipStream_t stream) {
  (void)in_sizes; (void)n_in; (void)out_size; (void)ws_size;
  const float* x         = (const float*)d_in[0];
  const float* xp        = (const float*)d_in[1];
  const float* qkv_w     = (const float*)d_in[2];
  const float* qkv_b     = (const float*)d_in[3];
  const float* proj_w    = (const float*)d_in[4];
  const float* proj_b    = (const float*)d_in[5];
  const float* rpb_table = (const float*)d_in[6];
  const float* rpb_nb    = (const float*)d_in[7];
  const float* rpb_win   = (const float*)d_in[8];

  char* ws = (char*)d_ws;
  size_t off = 0;
  auto alloc = [&](size_t bytes) -> void* {
    void* p = ws + off; off = (off + bytes + 255) & ~(size_t)255; return p;
  };
  short* w1       = (short*)alloc((size_t)576 * DIM * 2);
  short* w2       = (short*)alloc((size_t)DIM * DIM * 2);
  int2*  ring     = (int2*) alloc(132 * sizeof(int2));
  float* bias_tbl = (float*)alloc((size_t)HEADS * WA * NKEY * 4);
  short* qw       = (short*)alloc((size_t)2048 * WA * DIM * 2);
  short* kn       = (short*)alloc((size_t)8 * 112 * 112 * DIM * 2);
  short* vn       = (short*)alloc((size_t)8 * 112 * 112 * DIM * 2);
  short* kp       = (short*)alloc((size_t)2048 * DIM * 2);
  short* vp       = (short*)alloc((size_t)2048 * DIM * 2);
  short* ao       = (short*)alloc((size_t)2048 * WA * DIM * 2);
  // total ~157 MB of ws

  k_setup<<<dim3(64), dim3(256), 0, stream>>>(qkv_w, proj_w, rpb_table, rpb_nb, rpb_win,
                                              w1, w2, ring, bias_tbl);
  k_qkv_main<<<dim3(1568), dim3(256), 0, stream>>>(x, w1, qkv_b, qw, kn, vn);
  k_qkv_pool<<<dim3(32), dim3(256), 0, stream>>>(xp, w1, qkv_b, kp, vp);
  k_attn<<<dim3(12288), dim3(256), 0, stream>>>(qw, kn, vn, kp, vp, bias_tbl, ring, ao);
  k_proj<<<dim3(1568), dim3(256), 0, stream>>>(ao, w2, proj_b, (float*)d_out);
}

// Round 3
// 601.741 us; speedup vs baseline: 1.8577x; 1.8577x over previous
//
#include <hip/hip_runtime.h>
#include <stdint.h>

// WindowAttention (focal) on gfx950.
// Pipeline: k_setup -> k_qkv_main -> k_qkv_pool -> k_attn -> k_proj
// k_attn v3 (bisect of v2): R1-proven S_l / vT_l scalar LDS layouts
// + in-register softmax (bias/pmask in MFMA epilogue, shfl butterflies)
// + S_l overlays dead k_l/q_l -> 52 KB LDS -> 3 blocks/CU.

#define DIM 192
#define HEADS 6
#define HD 32
#define WA 49
#define NKEY 230
#define SSTR 272                 // S/P row stride in shorts (R1-proven, 16B-aligned rows)
#define VSTR 264                 // vT row stride in shorts (16B-aligned rows)
#define SCALE_F 0.17677669529663687f

typedef __attribute__((ext_vector_type(8))) short bf16x8;  // 8 bf16 in 4 VGPRs
typedef __attribute__((ext_vector_type(4))) float f32x4;

__device__ __forceinline__ short f2bf(float f) {
  union { float f; uint32_t u; } v; v.f = f;
  uint32_t u = v.u;
  return (short)((u + 0x7FFFu + ((u >> 16) & 1u)) >> 16);  // RNE
}

// ---------------- setup: bf16 weights, ring table, bias table ----------------
__global__ __launch_bounds__(256) void k_setup(
    const float* __restrict__ qkv_w, const float* __restrict__ proj_w,
    const float* __restrict__ rpb_table, const float* __restrict__ rpb_nb,
    const float* __restrict__ rpb_win,
    short* __restrict__ w1, short* __restrict__ w2,
    int2* __restrict__ ring, float* __restrict__ bias_tbl) {
  const int tid = blockIdx.x * blockDim.x + threadIdx.x;
  const int nth = gridDim.x * blockDim.x;
  for (int i = tid; i < 576 * DIM; i += nth) w1[i] = f2bf(qkv_w[i]);
  for (int i = tid; i < DIM * DIM; i += nth) w2[i] = f2bf(proj_w[i]);
  for (int e = tid; e < 132; e += nth) {
    int cnt = 0, fdr = 0, fdc = 0;
    for (int idx = 0; idx < 196; ++idx) {
      int s = idx / 49, rc = idx % 49, r = rc / 7, c = rc % 7;
      bool valid;
      if (s == 0)      valid = (r >= 4) || (c >= 4);
      else if (s == 1) valid = (r >= 4) || (c < 3);
      else if (s == 2) valid = (r < 3)  || (c >= 4);
      else             valid = (r < 3)  || (c < 3);
      if (valid) {
        if (cnt == e) { fdr = r + ((s < 2) ? 3 : -3); fdc = c + (((s & 1) == 0) ? 3 : -3); }
        ++cnt;
      }
    }
    ring[e] = make_int2(fdr, fdc);
  }
  for (int i = tid; i < HEADS * WA * NKEY; i += nth) {
    int kk = i % NKEY, rem = i / NKEY, r = rem % WA, h = rem / WA;
    float bv;
    if (kk < 49) {
      int ar = r / 7, ac = r % 7, br = kk / 7, bc = kk % 7;
      bv = rpb_table[((ar - br + 6) * 13 + (ac - bc + 6)) * HEADS + h];
    } else if (kk < 181) {
      bv = rpb_nb[((size_t)h * WA + r) * 132 + (kk - 49)];
    } else {
      int p = kk - 181;
      int ar = r / 7, ac = r % 7, br = p / 7, bc = p % 7;
      bv = rpb_win[h * 169 + (ar - br + 6) * 13 + (ac - bc + 6)];
    }
    bias_tbl[i] = bv;
  }
}

// ---------------- QKV on fine map: M=100352, N=576, K=192 ----------------
__global__ __launch_bounds__(256) void k_qkv_main(
    const float* __restrict__ x, const short* __restrict__ w1, const float* __restrict__ qkv_b,
    short* __restrict__ qw, short* __restrict__ kn, short* __restrict__ vn) {
  const int tid = threadIdx.x;
  const int wave = tid >> 6, lane = tid & 63, quad = lane >> 4, l16 = lane & 15;
  const int mbase = (blockIdx.x * 4 + wave) * 16;

  bf16x8 afr[6];
  {
    const float* xrow = x + (size_t)(mbase + l16) * DIM + quad * 8;
#pragma unroll
    for (int ks = 0; ks < 6; ++ks) {
      float4 f0 = *(const float4*)(xrow + ks * 32);
      float4 f1 = *(const float4*)(xrow + ks * 32 + 4);
      bf16x8 a;
      a[0] = f2bf(f0.x); a[1] = f2bf(f0.y); a[2] = f2bf(f0.z); a[3] = f2bf(f0.w);
      a[4] = f2bf(f1.x); a[5] = f2bf(f1.y); a[6] = f2bf(f1.z); a[7] = f2bf(f1.w);
      afr[ks] = a;
    }
  }
  size_t q_base[4], kv_base[4];
#pragma unroll
  for (int rg = 0; rg < 4; ++rg) {
    int m = mbase + quad * 4 + rg;
    int bb = m / 12544, rem = m % 12544;
    int i = rem / 112, j = rem % 112;
    int wr = i / 7, rr = i % 7, wc = j / 7, cc = j % 7;
    int winid = (bb * 16 + wr) * 16 + wc;
    q_base[rg]  = ((size_t)winid * WA + (rr * 7 + cc)) * DIM;
    kv_base[rg] = (size_t)m * DIM;
  }
  for (int nt = 0; nt < 36; ++nt) {
    const int n = nt * 16 + l16;
    const short* wrow = w1 + (size_t)n * DIM + quad * 8;
    f32x4 acc = {0.f, 0.f, 0.f, 0.f};
#pragma unroll
    for (int ks = 0; ks < 6; ++ks)
      acc = __builtin_amdgcn_mfma_f32_16x16x32_bf16(afr[ks], *(const bf16x8*)(wrow + ks * 32), acc, 0, 0, 0);
    const float bias = qkv_b[n];
#pragma unroll
    for (int rg = 0; rg < 4; ++rg) {
      float vo = acc[rg] + bias;
      if (nt < 12)      qw[q_base[rg] + n]            = f2bf(vo * SCALE_F);
      else if (nt < 24) kn[kv_base[rg] + (n - 192)]   = f2bf(vo);
      else              vn[kv_base[rg] + (n - 384)]   = f2bf(vo);
    }
  }
}

// ---------------- QKV on pooled map: M=2048, only k,v ----------------
__global__ __launch_bounds__(256) void k_qkv_pool(
    const float* __restrict__ xp, const short* __restrict__ w1, const float* __restrict__ qkv_b,
    short* __restrict__ kp, short* __restrict__ vp) {
  const int tid = threadIdx.x;
  const int wave = tid >> 6, lane = tid & 63, quad = lane >> 4, l16 = lane & 15;
  const int mbase = (blockIdx.x * 4 + wave) * 16;

  bf16x8 afr[6];
  {
    const float* xrow = xp + (size_t)(mbase + l16) * DIM + quad * 8;
#pragma unroll
    for (int ks = 0; ks < 6; ++ks) {
      float4 f0 = *(const float4*)(xrow + ks * 32);
      float4 f1 = *(const float4*)(xrow + ks * 32 + 4);
      bf16x8 a;
      a[0] = f2bf(f0.x); a[1] = f2bf(f0.y); a[2] = f2bf(f0.z); a[3] = f2bf(f0.w);
      a[4] = f2bf(f1.x); a[5] = f2bf(f1.y); a[6] = f2bf(f1.z); a[7] = f2bf(f1.w);
      afr[ks] = a;
    }
  }
  for (int nt = 12; nt < 36; ++nt) {
    const int n = nt * 16 + l16;
    const short* wrow = w1 + (size_t)n * DIM + quad * 8;
    f32x4 acc = {0.f, 0.f, 0.f, 0.f};
#pragma unroll
    for (int ks = 0; ks < 6; ++ks)
      acc = __builtin_amdgcn_mfma_f32_16x16x32_bf16(afr[ks], *(const bf16x8*)(wrow + ks * 32), acc, 0, 0, 0);
    const float bias = qkv_b[n];
#pragma unroll
    for (int rg = 0; rg < 4; ++rg) {
      int m = mbase + quad * 4 + rg;
      float vo = acc[rg] + bias;
      if (nt < 24) kp[(size_t)m * DIM + (n - 192)] = f2bf(vo);
      else         vp[(size_t)m * DIM + (n - 384)] = f2bf(vo);
    }
  }
}

// ---------------- attention v3: one block per (window, head) ----------------
// LDS map (bytes):
//   [0, 16896)        vT_l: 32 ch x VSTR(264) shorts  [ch][key], keys 230..255 zero
//   [16896, 41216)    phase<=2: k_l 240x40 shorts (19200) + q_l 64x40 shorts (5120)
//   [16896, 51712)    phase>=3: S_l 64 x SSTR(272) shorts (P, bf16)
//   [51712, 51968)    pmask[64] floats
__global__ __launch_bounds__(256, 3) void k_attn(
    const short* __restrict__ qw, const short* __restrict__ kn, const short* __restrict__ vn,
    const short* __restrict__ kpool, const short* __restrict__ vpool,
    const float* __restrict__ bias_tbl, const int2* __restrict__ ring,
    short* __restrict__ ao) {
  __shared__ __align__(16) char smem[51968];
  short* vT_l  = (short*)smem;
  short* k_l   = (short*)(smem + 16896);
  short* q_l   = (short*)(smem + 16896 + 19200);
  short* S_l   = (short*)(smem + 16896);          // overlay (phase >= 3)
  float* pmask = (float*)(smem + 51712);

  const int tid = threadIdx.x;
  const int bid = blockIdx.x;
  const int win = bid / HEADS;
  const int h   = bid - win * HEADS;
  const int b   = win >> 8;
  const int wr  = (win >> 4) & 15;
  const int wc  = win & 15;
  const int wave = tid >> 6, lane = tid & 63, quad = lane >> 4, l16 = lane & 15;

  // ---- phase 0: zero pads
  {
    int* kli = (int*)k_l;
    for (int i = tid; i < 200; i += 256) kli[4600 + i] = 0;         // k_l rows 230..239
    int* qli = (int*)q_l;
    for (int i = tid; i < 300; i += 256) qli[980 + i] = 0;          // q_l rows 49..63
    if (tid < 128) {                                                 // vT_l keys 224..255
      int ch = tid >> 2, j = tid & 3;
      *(int4*)&vT_l[ch * VSTR + 224 + j * 8] = make_int4(0, 0, 0, 0);
    }
    if (tid < 64) {
      float pm = 0.f;
      if (tid < WA) {
        int pi = wr - 3 + tid / 7, pj = wc - 3 + tid % 7;
        if (pi < 0 || pi >= 16 || pj < 0 || pj >= 16) pm = -100.f;
      }
      pmask[tid] = pm;
    }
  }
  __syncthreads();

  // ---- phase 1: gather q, K, V^T (R1-proven scalar transpose writes)
  if (tid < 196) {
    int r = tid >> 2, part = tid & 3;
    *(int4*)&q_l[r * 40 + part * 8] =
        *(const int4*)(qw + ((size_t)win * WA + r) * DIM + h * HD + part * 8);
  }
  {
    const int part = tid & 3;
    const int choff = h * HD + part * 8;
    for (int it = 0; it < 4; ++it) {
      int kk = it * 64 + (tid >> 2);
      if (kk < NKEY) {
        int4 kvv = make_int4(0, 0, 0, 0), vvv = make_int4(0, 0, 0, 0);
        const short* ksrc = nullptr; const short* vsrc = nullptr;
        if (kk < WA) {
          int i = wr * 7 + kk / 7, j = wc * 7 + kk % 7;
          size_t t = ((size_t)(b * 112 + i)) * 112 + j;
          ksrc = kn + t * DIM + choff; vsrc = vn + t * DIM + choff;
        } else if (kk < 181) {
          int2 rr = ring[kk - 49];
          int i = wr * 7 + rr.x; if (i < 0) i += 112; if (i >= 112) i -= 112;
          int j = wc * 7 + rr.y; if (j < 0) j += 112; if (j >= 112) j -= 112;
          size_t t = ((size_t)(b * 112 + i)) * 112 + j;
          ksrc = kn + t * DIM + choff; vsrc = vn + t * DIM + choff;
        } else {
          int p = kk - 181;
          int i = wr - 3 + p / 7, j = wc - 3 + p % 7;
          if (i >= 0 && i < 16 && j >= 0 && j < 16) {
            size_t t = ((size_t)(b * 16 + i)) * 16 + j;
            ksrc = kpool + t * DIM + choff; vsrc = vpool + t * DIM + choff;
          }
        }
        if (ksrc) { kvv = *(const int4*)ksrc; vvv = *(const int4*)vsrc; }
        *(int4*)&k_l[kk * 40 + part * 8] = kvv;   // zeros for OOB pooled keys
        const short* vs = (const short*)&vvv;
#pragma unroll
        for (int e = 0; e < 8; ++e) vT_l[(part * 8 + e) * VSTR + kk] = vs[e];
      }
    }
  }
  __syncthreads();

  // ---- phase 2: S = qK^T (regs) + bias + pool mask + in-register softmax
  f32x4 acc[15];
  {
    bf16x8 qfr = *(const bf16x8*)&q_l[(wave * 16 + l16) * 40 + quad * 8];
#pragma unroll
    for (int nt = 0; nt < 15; ++nt) {
      bf16x8 kfr = *(const bf16x8*)&k_l[(nt * 16 + l16) * 40 + quad * 8];
      f32x4 z = {0.f, 0.f, 0.f, 0.f};
      acc[nt] = __builtin_amdgcn_mfma_f32_16x16x32_bf16(qfr, kfr, z, 0, 0, 0);
    }
  }
  const int rowb = wave * 16 + quad * 4;
#pragma unroll
  for (int nt = 0; nt < 15; ++nt) {
    const int key = nt * 16 + l16;
    const bool kval = key < NKEY;
    const float pm = (key >= 181 && kval) ? pmask[key - 181] : 0.f;
#pragma unroll
    for (int rg = 0; rg < 4; ++rg) {
      const int row = rowb + rg;
      float bv = (kval && row < WA) ? bias_tbl[(h * WA + row) * NKEY + key] : 0.f;
      acc[nt][rg] = kval ? (acc[nt][rg] + bv + pm) : -1e30f;
    }
  }
  float m4[4] = {-1e30f, -1e30f, -1e30f, -1e30f};
#pragma unroll
  for (int nt = 0; nt < 15; ++nt)
#pragma unroll
    for (int rg = 0; rg < 4; ++rg) m4[rg] = fmaxf(m4[rg], acc[nt][rg]);
#pragma unroll
  for (int msk = 1; msk <= 8; msk <<= 1)
#pragma unroll
    for (int rg = 0; rg < 4; ++rg) m4[rg] = fmaxf(m4[rg], __shfl_xor(m4[rg], msk));
  float s4[4] = {0.f, 0.f, 0.f, 0.f};
#pragma unroll
  for (int nt = 0; nt < 15; ++nt)
#pragma unroll
    for (int rg = 0; rg < 4; ++rg) {
      float e = __expf(acc[nt][rg] - m4[rg]);
      acc[nt][rg] = e; s4[rg] += e;
    }
#pragma unroll
  for (int msk = 1; msk <= 8; msk <<= 1)
#pragma unroll
    for (int rg = 0; rg < 4; ++rg) s4[rg] += __shfl_xor(s4[rg], msk);
  float inv4[4];
#pragma unroll
  for (int rg = 0; rg < 4; ++rg) inv4[rg] = 1.f / s4[rg];
#pragma unroll
  for (int nt = 0; nt < 15; ++nt)
#pragma unroll
    for (int rg = 0; rg < 4; ++rg) acc[nt][rg] *= inv4[rg];

  __syncthreads();   // k_l / q_l dead; S_l (P) takes over the region

  // ---- phase 3: store P to S_l (R1-proven D-layout store) + zero cols 240..255
#pragma unroll
  for (int nt = 0; nt < 15; ++nt)
#pragma unroll
    for (int rg = 0; rg < 4; ++rg)
      S_l[(rowb + rg) * SSTR + nt * 16 + l16] = f2bf(acc[nt][rg]);
  {
    int rr = tid >> 2, c0 = 240 + (tid & 3) * 4;
    *(int2*)&S_l[rr * SSTR + c0] = make_int2(0, 0);
  }
  __syncthreads();

  // ---- phase 4: O = P V  (R1-proven read patterns)
#pragma unroll
  for (int nt2 = 0; nt2 < 2; ++nt2) {
    f32x4 acc2 = {0.f, 0.f, 0.f, 0.f};
#pragma unroll
    for (int k0 = 0; k0 < 8; ++k0) {
      bf16x8 pfr = *(const bf16x8*)&S_l[(wave * 16 + l16) * SSTR + k0 * 32 + quad * 8];
      bf16x8 vfr = *(const bf16x8*)&vT_l[(nt2 * 16 + l16) * VSTR + k0 * 32 + quad * 8];
      acc2 = __builtin_amdgcn_mfma_f32_16x16x32_bf16(pfr, vfr, acc2, 0, 0, 0);
    }
#pragma unroll
    for (int rg = 0; rg < 4; ++rg) {
      int row = rowb + rg;
      if (row < WA)
        ao[((size_t)win * WA + row) * DIM + h * HD + nt2 * 16 + l16] = f2bf(acc2[rg]);
    }
  }
}

// ---------------- proj: M=100352, N=192, K=192, fp32 out ----------------
__global__ __launch_bounds__(256) void k_proj(
    const short* __restrict__ ao, const short* __restrict__ w2, const float* __restrict__ pb,
    float* __restrict__ out) {
  const int tid = threadIdx.x;
  const int wave = tid >> 6, lane = tid & 63, quad = lane >> 4, l16 = lane & 15;
  const int mbase = (blockIdx.x * 4 + wave) * 16;
  bf16x8 afr[6];
  const short* arow = ao + (size_t)(mbase + l16) * DIM + quad * 8;
#pragma unroll
  for (int ks = 0; ks < 6; ++ks) afr[ks] = *(const bf16x8*)(arow + ks * 32);
  for (int nt = 0; nt < 12; ++nt) {
    const int n = nt * 16 + l16;
    const short* wrow = w2 + (size_t)n * DIM + quad * 8;
    f32x4 acc = {0.f, 0.f, 0.f, 0.f};
#pragma unroll
    for (int ks = 0; ks < 6; ++ks)
      acc = __builtin_amdgcn_mfma_f32_16x16x32_bf16(afr[ks], *(const bf16x8*)(wrow + ks * 32), acc, 0, 0, 0);
    const float bias = pb[n];
#pragma unroll
    for (int rg = 0; rg < 4; ++rg)
      out[(size_t)(mbase + quad * 4 + rg) * DIM + n] = acc[rg] + bias;
  }
}

extern "C" void kernel_launch(void* const* d_in, const int* in_sizes, int n_in,
                              void* d_out, int out_size, void* d_ws, size_t ws_size,
                              hipStream_t stream) {
  (void)in_sizes; (void)n_in; (void)out_size; (void)ws_size;
  const float* x         = (const float*)d_in[0];
  const float* xp        = (const float*)d_in[1];
  const float* qkv_w     = (const float*)d_in[2];
  const float* qkv_b     = (const float*)d_in[3];
  const float* proj_w    = (const float*)d_in[4];
  const float* proj_b    = (const float*)d_in[5];
  const float* rpb_table = (const float*)d_in[6];
  const float* rpb_nb    = (const float*)d_in[7];
  const float* rpb_win   = (const float*)d_in[8];

  char* ws = (char*)d_ws;
  size_t off = 0;
  auto alloc = [&](size_t bytes) -> void* {
    void* p = ws + off; off = (off + bytes + 255) & ~(size_t)255; return p;
  };
  short* w1       = (short*)alloc((size_t)576 * DIM * 2);
  short* w2       = (short*)alloc((size_t)DIM * DIM * 2);
  int2*  ring     = (int2*) alloc(132 * sizeof(int2));
  float* bias_tbl = (float*)alloc((size_t)HEADS * WA * NKEY * 4);
  short* qw       = (short*)alloc((size_t)2048 * WA * DIM * 2);
  short* kn       = (short*)alloc((size_t)8 * 112 * 112 * DIM * 2);
  short* vn       = (short*)alloc((size_t)8 * 112 * 112 * DIM * 2);
  short* kp       = (short*)alloc((size_t)2048 * DIM * 2);
  short* vp       = (short*)alloc((size_t)2048 * DIM * 2);
  short* ao       = (short*)alloc((size_t)2048 * WA * DIM * 2);

  k_setup<<<dim3(64), dim3(256), 0, stream>>>(qkv_w, proj_w, rpb_table, rpb_nb, rpb_win,
                                              w1, w2, ring, bias_tbl);
  k_qkv_main<<<dim3(1568), dim3(256), 0, stream>>>(x, w1, qkv_b, qw, kn, vn);
  k_qkv_pool<<<dim3(32), dim3(256), 0, stream>>>(xp, w1, qkv_b, kp, vp);
  k_attn<<<dim3(12288), dim3(256), 0, stream>>>(qw, kn, vn, kp, vp, bias_tbl, ring, ao);
  k_proj<<<dim3(1568), dim3(256), 0, stream>>>(ao, w2, proj_b, (float*)d_out);
}

// Round 4
// 498.385 us; speedup vs baseline: 2.2429x; 1.2074x over previous
//
#include <hip/hip_runtime.h>
#include <stdint.h>

// WindowAttention (focal) on gfx950.
// Pipeline: k_setup -> k_qkv_main -> k_qkv_pool -> k_attn -> k_proj
// R4: k_qkv_main/k_proj restructured: M=128/block, double-buffered LDS weight
// staging, weights pre-swizzled into MFMA fragment order (w1s/w2s) so staging
// writes and ds_read_b128 fragment reads are both 2-way (free). k_attn = R3.

#define DIM 192
#define HEADS 6
#define HD 32
#define WA 49
#define NKEY 230
#define SSTR 272                 // S/P row stride in shorts (R1-proven)
#define VSTR 264                 // vT row stride in shorts
#define SCALE_F 0.17677669529663687f

typedef __attribute__((ext_vector_type(8))) short bf16x8;  // 8 bf16 in 4 VGPRs
typedef __attribute__((ext_vector_type(4))) float f32x4;

__device__ __forceinline__ short f2bf(float f) {
  union { float f; uint32_t u; } v; v.f = f;
  uint32_t u = v.u;
  return (short)((u + 0x7FFFu + ((u >> 16) & 1u)) >> 16);  // RNE
}

// ---------------- setup: bf16 weights (plain + fragment-swizzled), tables ----
// Swizzle: tile t = 32 rows; frag (ntl,ks,quad,l16) holds w[t*32+ntl*16+l16]
// [ks*32+quad*8 .. +8). Tile = 6144 shorts.
__global__ __launch_bounds__(256) void k_setup(
    const float* __restrict__ qkv_w, const float* __restrict__ proj_w,
    const float* __restrict__ rpb_table, const float* __restrict__ rpb_nb,
    const float* __restrict__ rpb_win,
    short* __restrict__ w1, short* __restrict__ w1s, short* __restrict__ w2s,
    int2* __restrict__ ring, float* __restrict__ bias_tbl) {
  const int tid = blockIdx.x * blockDim.x + threadIdx.x;
  const int nth = gridDim.x * blockDim.x;
  for (int i = tid; i < 576 * DIM; i += nth) {
    float fv = qkv_w[i];
    w1[i] = f2bf(fv);
    int r = i / DIM, c = i % DIM;
    int t = r >> 5, ntl = (r >> 4) & 1, lr = r & 15;
    int ks = c >> 5, quad = (c >> 3) & 3, e = c & 7;
    w1s[t * 6144 + (((ntl * 6 + ks) * 4 + quad) * 16 + lr) * 8 + e] = f2bf(fv);
  }
  for (int i = tid; i < DIM * DIM; i += nth) {
    int r = i / DIM, c = i % DIM;
    int t = r >> 5, ntl = (r >> 4) & 1, lr = r & 15;
    int ks = c >> 5, quad = (c >> 3) & 3, e = c & 7;
    w2s[t * 6144 + (((ntl * 6 + ks) * 4 + quad) * 16 + lr) * 8 + e] = f2bf(proj_w[i]);
  }
  for (int e = tid; e < 132; e += nth) {
    int cnt = 0, fdr = 0, fdc = 0;
    for (int idx = 0; idx < 196; ++idx) {
      int s = idx / 49, rc = idx % 49, r = rc / 7, c = rc % 7;
      bool valid;
      if (s == 0)      valid = (r >= 4) || (c >= 4);
      else if (s == 1) valid = (r >= 4) || (c < 3);
      else if (s == 2) valid = (r < 3)  || (c >= 4);
      else             valid = (r < 3)  || (c < 3);
      if (valid) {
        if (cnt == e) { fdr = r + ((s < 2) ? 3 : -3); fdc = c + (((s & 1) == 0) ? 3 : -3); }
        ++cnt;
      }
    }
    ring[e] = make_int2(fdr, fdc);
  }
  for (int i = tid; i < HEADS * WA * NKEY; i += nth) {
    int kk = i % NKEY, rem = i / NKEY, r = rem % WA, h = rem / WA;
    float bv;
    if (kk < 49) {
      int ar = r / 7, ac = r % 7, br = kk / 7, bc = kk % 7;
      bv = rpb_table[((ar - br + 6) * 13 + (ac - bc + 6)) * HEADS + h];
    } else if (kk < 181) {
      bv = rpb_nb[((size_t)h * WA + r) * 132 + (kk - 49)];
    } else {
      int p = kk - 181;
      int ar = r / 7, ac = r % 7, br = p / 7, bc = p % 7;
      bv = rpb_win[h * 169 + (ar - br + 6) * 13 + (ac - bc + 6)];
    }
    bias_tbl[i] = bv;
  }
}

// ---------------- QKV on fine map: M=100352, N=576, K=192 ----------------
// 128 rows/block, double-buffered LDS weight tiles (32 cols x 192 ch).
__global__ __launch_bounds__(256, 4) void k_qkv_main(
    const float* __restrict__ x, const short* __restrict__ w1s, const float* __restrict__ qkv_b,
    short* __restrict__ qw, short* __restrict__ kn, short* __restrict__ vn) {
  __shared__ __align__(16) short wbuf[2][6144];
  const int tid = threadIdx.x;
  const int wave = tid >> 6, lane = tid & 63, quad = lane >> 4, l16 = lane & 15;
  const int mbase = blockIdx.x * 128;

  bf16x8 afr[2][6];
#pragma unroll
  for (int mt = 0; mt < 2; ++mt) {
    const float* xrow = x + (size_t)(mbase + wave * 32 + mt * 16 + l16) * DIM + quad * 8;
#pragma unroll
    for (int ks = 0; ks < 6; ++ks) {
      float4 f0 = *(const float4*)(xrow + ks * 32);
      float4 f1 = *(const float4*)(xrow + ks * 32 + 4);
      bf16x8 a;
      a[0] = f2bf(f0.x); a[1] = f2bf(f0.y); a[2] = f2bf(f0.z); a[3] = f2bf(f0.w);
      a[4] = f2bf(f1.x); a[5] = f2bf(f1.y); a[6] = f2bf(f1.z); a[7] = f2bf(f1.w);
      afr[mt][ks] = a;
    }
  }
  uint32_t q_base[2][4], kv_base[2][4];
#pragma unroll
  for (int mt = 0; mt < 2; ++mt)
#pragma unroll
    for (int rg = 0; rg < 4; ++rg) {
      int m = mbase + wave * 32 + mt * 16 + quad * 4 + rg;
      int bb = m / 12544, rem = m % 12544;
      int i = rem / 112, j = rem % 112;
      int wr = i / 7, rr = i % 7, wc = j / 7, cc = j % 7;
      int winid = (bb * 16 + wr) * 16 + wc;
      q_base[mt][rg]  = ((uint32_t)winid * WA + (rr * 7 + cc)) * DIM;
      kv_base[mt][rg] = (uint32_t)m * DIM;
    }

  int4 st[3];
  {
    const int4* src = (const int4*)w1s + tid;
#pragma unroll
    for (int it = 0; it < 3; ++it) st[it] = src[it * 256];
  }
  for (int t = 0; t < 18; ++t) {
    short* buf = wbuf[t & 1];
#pragma unroll
    for (int it = 0; it < 3; ++it) ((int4*)buf)[tid + it * 256] = st[it];
    __syncthreads();
    if (t < 17) {
      const int4* src = (const int4*)(w1s + (t + 1) * 6144) + tid;
#pragma unroll
      for (int it = 0; it < 3; ++it) st[it] = src[it * 256];
    }
#pragma unroll
    for (int ntl = 0; ntl < 2; ++ntl) {
      const int n = t * 32 + ntl * 16 + l16;
      bf16x8 bfr[6];
#pragma unroll
      for (int ks = 0; ks < 6; ++ks)
        bfr[ks] = *(const bf16x8*)&buf[(((ntl * 6 + ks) * 4 + quad) * 16 + l16) * 8];
      const float bias = qkv_b[n];
#pragma unroll
      for (int mt = 0; mt < 2; ++mt) {
        f32x4 acc = {0.f, 0.f, 0.f, 0.f};
#pragma unroll
        for (int ks = 0; ks < 6; ++ks)
          acc = __builtin_amdgcn_mfma_f32_16x16x32_bf16(afr[mt][ks], bfr[ks], acc, 0, 0, 0);
#pragma unroll
        for (int rg = 0; rg < 4; ++rg) {
          float vo = acc[rg] + bias;
          if (t < 6)       qw[q_base[mt][rg] + n]           = f2bf(vo * SCALE_F);
          else if (t < 12) kn[kv_base[mt][rg] + (n - 192)]  = f2bf(vo);
          else             vn[kv_base[mt][rg] + (n - 384)]  = f2bf(vo);
        }
      }
    }
  }
}

// ---------------- QKV on pooled map: M=2048, only k,v (R3-proven) ----------
__global__ __launch_bounds__(256) void k_qkv_pool(
    const float* __restrict__ xp, const short* __restrict__ w1, const float* __restrict__ qkv_b,
    short* __restrict__ kp, short* __restrict__ vp) {
  const int tid = threadIdx.x;
  const int wave = tid >> 6, lane = tid & 63, quad = lane >> 4, l16 = lane & 15;
  const int mbase = (blockIdx.x * 4 + wave) * 16;

  bf16x8 afr[6];
  {
    const float* xrow = xp + (size_t)(mbase + l16) * DIM + quad * 8;
#pragma unroll
    for (int ks = 0; ks < 6; ++ks) {
      float4 f0 = *(const float4*)(xrow + ks * 32);
      float4 f1 = *(const float4*)(xrow + ks * 32 + 4);
      bf16x8 a;
      a[0] = f2bf(f0.x); a[1] = f2bf(f0.y); a[2] = f2bf(f0.z); a[3] = f2bf(f0.w);
      a[4] = f2bf(f1.x); a[5] = f2bf(f1.y); a[6] = f2bf(f1.z); a[7] = f2bf(f1.w);
      afr[ks] = a;
    }
  }
  for (int nt = 12; nt < 36; ++nt) {
    const int n = nt * 16 + l16;
    const short* wrow = w1 + (size_t)n * DIM + quad * 8;
    f32x4 acc = {0.f, 0.f, 0.f, 0.f};
#pragma unroll
    for (int ks = 0; ks < 6; ++ks)
      acc = __builtin_amdgcn_mfma_f32_16x16x32_bf16(afr[ks], *(const bf16x8*)(wrow + ks * 32), acc, 0, 0, 0);
    const float bias = qkv_b[n];
#pragma unroll
    for (int rg = 0; rg < 4; ++rg) {
      int m = mbase + quad * 4 + rg;
      float vo = acc[rg] + bias;
      if (nt < 24) kp[(size_t)m * DIM + (n - 192)] = f2bf(vo);
      else         vp[(size_t)m * DIM + (n - 384)] = f2bf(vo);
    }
  }
}

// ---------------- attention v3 (R3-proven, unchanged) ----------------
__global__ __launch_bounds__(256, 3) void k_attn(
    const short* __restrict__ qw, const short* __restrict__ kn, const short* __restrict__ vn,
    const short* __restrict__ kpool, const short* __restrict__ vpool,
    const float* __restrict__ bias_tbl, const int2* __restrict__ ring,
    short* __restrict__ ao) {
  __shared__ __align__(16) char smem[51968];
  short* vT_l  = (short*)smem;
  short* k_l   = (short*)(smem + 16896);
  short* q_l   = (short*)(smem + 16896 + 19200);
  short* S_l   = (short*)(smem + 16896);          // overlay (phase >= 3)
  float* pmask = (float*)(smem + 51712);

  const int tid = threadIdx.x;
  const int bid = blockIdx.x;
  const int win = bid / HEADS;
  const int h   = bid - win * HEADS;
  const int b   = win >> 8;
  const int wr  = (win >> 4) & 15;
  const int wc  = win & 15;
  const int wave = tid >> 6, lane = tid & 63, quad = lane >> 4, l16 = lane & 15;

  {
    int* kli = (int*)k_l;
    for (int i = tid; i < 200; i += 256) kli[4600 + i] = 0;
    int* qli = (int*)q_l;
    for (int i = tid; i < 300; i += 256) qli[980 + i] = 0;
    if (tid < 128) {
      int ch = tid >> 2, j = tid & 3;
      *(int4*)&vT_l[ch * VSTR + 224 + j * 8] = make_int4(0, 0, 0, 0);
    }
    if (tid < 64) {
      float pm = 0.f;
      if (tid < WA) {
        int pi = wr - 3 + tid / 7, pj = wc - 3 + tid % 7;
        if (pi < 0 || pi >= 16 || pj < 0 || pj >= 16) pm = -100.f;
      }
      pmask[tid] = pm;
    }
  }
  __syncthreads();

  if (tid < 196) {
    int r = tid >> 2, part = tid & 3;
    *(int4*)&q_l[r * 40 + part * 8] =
        *(const int4*)(qw + ((size_t)win * WA + r) * DIM + h * HD + part * 8);
  }
  {
    const int part = tid & 3;
    const int choff = h * HD + part * 8;
    for (int it = 0; it < 4; ++it) {
      int kk = it * 64 + (tid >> 2);
      if (kk < NKEY) {
        int4 kvv = make_int4(0, 0, 0, 0), vvv = make_int4(0, 0, 0, 0);
        const short* ksrc = nullptr; const short* vsrc = nullptr;
        if (kk < WA) {
          int i = wr * 7 + kk / 7, j = wc * 7 + kk % 7;
          size_t t = ((size_t)(b * 112 + i)) * 112 + j;
          ksrc = kn + t * DIM + choff; vsrc = vn + t * DIM + choff;
        } else if (kk < 181) {
          int2 rr = ring[kk - 49];
          int i = wr * 7 + rr.x; if (i < 0) i += 112; if (i >= 112) i -= 112;
          int j = wc * 7 + rr.y; if (j < 0) j += 112; if (j >= 112) j -= 112;
          size_t t = ((size_t)(b * 112 + i)) * 112 + j;
          ksrc = kn + t * DIM + choff; vsrc = vn + t * DIM + choff;
        } else {
          int p = kk - 181;
          int i = wr - 3 + p / 7, j = wc - 3 + p % 7;
          if (i >= 0 && i < 16 && j >= 0 && j < 16) {
            size_t t = ((size_t)(b * 16 + i)) * 16 + j;
            ksrc = kpool + t * DIM + choff; vsrc = vpool + t * DIM + choff;
          }
        }
        if (ksrc) { kvv = *(const int4*)ksrc; vvv = *(const int4*)vsrc; }
        *(int4*)&k_l[kk * 40 + part * 8] = kvv;
        const short* vs = (const short*)&vvv;
#pragma unroll
        for (int e = 0; e < 8; ++e) vT_l[(part * 8 + e) * VSTR + kk] = vs[e];
      }
    }
  }
  __syncthreads();

  f32x4 acc[15];
  {
    bf16x8 qfr = *(const bf16x8*)&q_l[(wave * 16 + l16) * 40 + quad * 8];
#pragma unroll
    for (int nt = 0; nt < 15; ++nt) {
      bf16x8 kfr = *(const bf16x8*)&k_l[(nt * 16 + l16) * 40 + quad * 8];
      f32x4 z = {0.f, 0.f, 0.f, 0.f};
      acc[nt] = __builtin_amdgcn_mfma_f32_16x16x32_bf16(qfr, kfr, z, 0, 0, 0);
    }
  }
  const int rowb = wave * 16 + quad * 4;
#pragma unroll
  for (int nt = 0; nt < 15; ++nt) {
    const int key = nt * 16 + l16;
    const bool kval = key < NKEY;
    const float pm = (key >= 181 && kval) ? pmask[key - 181] : 0.f;
#pragma unroll
    for (int rg = 0; rg < 4; ++rg) {
      const int row = rowb + rg;
      float bv = (kval && row < WA) ? bias_tbl[(h * WA + row) * NKEY + key] : 0.f;
      acc[nt][rg] = kval ? (acc[nt][rg] + bv + pm) : -1e30f;
    }
  }
  float m4[4] = {-1e30f, -1e30f, -1e30f, -1e30f};
#pragma unroll
  for (int nt = 0; nt < 15; ++nt)
#pragma unroll
    for (int rg = 0; rg < 4; ++rg) m4[rg] = fmaxf(m4[rg], acc[nt][rg]);
#pragma unroll
  for (int msk = 1; msk <= 8; msk <<= 1)
#pragma unroll
    for (int rg = 0; rg < 4; ++rg) m4[rg] = fmaxf(m4[rg], __shfl_xor(m4[rg], msk));
  float s4[4] = {0.f, 0.f, 0.f, 0.f};
#pragma unroll
  for (int nt = 0; nt < 15; ++nt)
#pragma unroll
    for (int rg = 0; rg < 4; ++rg) {
      float e = __expf(acc[nt][rg] - m4[rg]);
      acc[nt][rg] = e; s4[rg] += e;
    }
#pragma unroll
  for (int msk = 1; msk <= 8; msk <<= 1)
#pragma unroll
    for (int rg = 0; rg < 4; ++rg) s4[rg] += __shfl_xor(s4[rg], msk);
  float inv4[4];
#pragma unroll
  for (int rg = 0; rg < 4; ++rg) inv4[rg] = 1.f / s4[rg];
#pragma unroll
  for (int nt = 0; nt < 15; ++nt)
#pragma unroll
    for (int rg = 0; rg < 4; ++rg) acc[nt][rg] *= inv4[rg];

  __syncthreads();

#pragma unroll
  for (int nt = 0; nt < 15; ++nt)
#pragma unroll
    for (int rg = 0; rg < 4; ++rg)
      S_l[(rowb + rg) * SSTR + nt * 16 + l16] = f2bf(acc[nt][rg]);
  {
    int rr = tid >> 2, c0 = 240 + (tid & 3) * 4;
    *(int2*)&S_l[rr * SSTR + c0] = make_int2(0, 0);
  }
  __syncthreads();

#pragma unroll
  for (int nt2 = 0; nt2 < 2; ++nt2) {
    f32x4 acc2 = {0.f, 0.f, 0.f, 0.f};
#pragma unroll
    for (int k0 = 0; k0 < 8; ++k0) {
      bf16x8 pfr = *(const bf16x8*)&S_l[(wave * 16 + l16) * SSTR + k0 * 32 + quad * 8];
      bf16x8 vfr = *(const bf16x8*)&vT_l[(nt2 * 16 + l16) * VSTR + k0 * 32 + quad * 8];
      acc2 = __builtin_amdgcn_mfma_f32_16x16x32_bf16(pfr, vfr, acc2, 0, 0, 0);
    }
#pragma unroll
    for (int rg = 0; rg < 4; ++rg) {
      int row = rowb + rg;
      if (row < WA)
        ao[((size_t)win * WA + row) * DIM + h * HD + nt2 * 16 + l16] = f2bf(acc2[rg]);
    }
  }
}

// ---------------- proj: M=100352, N=192, K=192, fp32 out ----------------
__global__ __launch_bounds__(256, 4) void k_proj(
    const short* __restrict__ ao, const short* __restrict__ w2s, const float* __restrict__ pb,
    float* __restrict__ out) {
  __shared__ __align__(16) short wbuf[2][6144];
  const int tid = threadIdx.x;
  const int wave = tid >> 6, lane = tid & 63, quad = lane >> 4, l16 = lane & 15;
  const int mbase = blockIdx.x * 128;

  bf16x8 afr[2][6];
#pragma unroll
  for (int mt = 0; mt < 2; ++mt) {
    const short* arow = ao + (size_t)(mbase + wave * 32 + mt * 16 + l16) * DIM + quad * 8;
#pragma unroll
    for (int ks = 0; ks < 6; ++ks) afr[mt][ks] = *(const bf16x8*)(arow + ks * 32);
  }
  int4 st[3];
  {
    const int4* src = (const int4*)w2s + tid;
#pragma unroll
    for (int it = 0; it < 3; ++it) st[it] = src[it * 256];
  }
  for (int t = 0; t < 6; ++t) {
    short* buf = wbuf[t & 1];
#pragma unroll
    for (int it = 0; it < 3; ++it) ((int4*)buf)[tid + it * 256] = st[it];
    __syncthreads();
    if (t < 5) {
      const int4* src = (const int4*)(w2s + (t + 1) * 6144) + tid;
#pragma unroll
      for (int it = 0; it < 3; ++it) st[it] = src[it * 256];
    }
#pragma unroll
    for (int ntl = 0; ntl < 2; ++ntl) {
      const int n = t * 32 + ntl * 16 + l16;
      bf16x8 bfr[6];
#pragma unroll
      for (int ks = 0; ks < 6; ++ks)
        bfr[ks] = *(const bf16x8*)&buf[(((ntl * 6 + ks) * 4 + quad) * 16 + l16) * 8];
      const float bias = pb[n];
#pragma unroll
      for (int mt = 0; mt < 2; ++mt) {
        f32x4 acc = {0.f, 0.f, 0.f, 0.f};
#pragma unroll
        for (int ks = 0; ks < 6; ++ks)
          acc = __builtin_amdgcn_mfma_f32_16x16x32_bf16(afr[mt][ks], bfr[ks], acc, 0, 0, 0);
#pragma unroll
        for (int rg = 0; rg < 4; ++rg)
          out[(size_t)(mbase + wave * 32 + mt * 16 + quad * 4 + rg) * DIM + n] = acc[rg] + bias;
      }
    }
  }
}

extern "C" void kernel_launch(void* const* d_in, const int* in_sizes, int n_in,
                              void* d_out, int out_size, void* d_ws, size_t ws_size,
                              hipStream_t stream) {
  (void)in_sizes; (void)n_in; (void)out_size; (void)ws_size;
  const float* x         = (const float*)d_in[0];
  const float* xp        = (const float*)d_in[1];
  const float* qkv_w     = (const float*)d_in[2];
  const float* qkv_b     = (const float*)d_in[3];
  const float* proj_w    = (const float*)d_in[4];
  const float* proj_b    = (const float*)d_in[5];
  const float* rpb_table = (const float*)d_in[6];
  const float* rpb_nb    = (const float*)d_in[7];
  const float* rpb_win   = (const float*)d_in[8];

  char* ws = (char*)d_ws;
  size_t off = 0;
  auto alloc = [&](size_t bytes) -> void* {
    void* p = ws + off; off = (off + bytes + 255) & ~(size_t)255; return p;
  };
  short* w1       = (short*)alloc((size_t)576 * DIM * 2);
  short* w1s      = (short*)alloc((size_t)576 * DIM * 2);
  short* w2s      = (short*)alloc((size_t)DIM * DIM * 2);
  int2*  ring     = (int2*) alloc(132 * sizeof(int2));
  float* bias_tbl = (float*)alloc((size_t)HEADS * WA * NKEY * 4);
  short* qw       = (short*)alloc((size_t)2048 * WA * DIM * 2);
  short* kn       = (short*)alloc((size_t)8 * 112 * 112 * DIM * 2);
  short* vn       = (short*)alloc((size_t)8 * 112 * 112 * DIM * 2);
  short* kp       = (short*)alloc((size_t)2048 * DIM * 2);
  short* vp       = (short*)alloc((size_t)2048 * DIM * 2);
  short* ao       = (short*)alloc((size_t)2048 * WA * DIM * 2);

  k_setup<<<dim3(64), dim3(256), 0, stream>>>(qkv_w, proj_w, rpb_table, rpb_nb, rpb_win,
                                              w1, w1s, w2s, ring, bias_tbl);
  k_qkv_main<<<dim3(784), dim3(256), 0, stream>>>(x, w1s, qkv_b, qw, kn, vn);
  k_qkv_pool<<<dim3(32), dim3(256), 0, stream>>>(xp, w1, qkv_b, kp, vp);
  k_attn<<<dim3(12288), dim3(256), 0, stream>>>(qw, kn, vn, kp, vp, bias_tbl, ring, ao);
  k_proj<<<dim3(784), dim3(256), 0, stream>>>(ao, w2s, proj_b, (float*)d_out);
}